// Round 3
// baseline (259.104 us; speedup 1.0000x reference)
//
#include <hip/hip_runtime.h>

// N=100000, E=3200000, H=256, G=128.
// R9: ABLATION — drop the entire LDS counting-sort / bucket pipeline.
// R7 lesson: removing the s1+s_scan front-end (2 dispatches, ~15MB traffic)
// changed nothing (131.9 -> 135.8us) => the bucket machinery's cost is in its
// shared structure (2 LDS passes, scans, pairs round-trip, 3 dependent
// dispatches), not the front-end. Pure-traffic roofline is ~10us; we're ~13x
// above => latency/serialization-bound, not BW-bound.
// New structure: direct fire-and-forget global_atomic_add_f32 into agg[N]
// (400KB, fully L2-resident; ~32 adds/address over the whole kernel => low
// contention), then one fused node-MLP + pool + ticket-epilogue kernel.
//   memset(agg+hdr, ~402KB) -> e_scatter (int4 edge reads, 4 atomics/quad)
//   -> n_node (collapsed MLP f(a)=sum_k relu(a*Wl[k]+bl[k])*Wo[k], LDS
//   per-graph pooling, device-scope ticket epilogue writes out[G]).
// HBM budget: 25.6MB edges + L2-hot x gather + 0.8MB agg r/w + 0.4MB batch.

#define GMAX  128      // max graphs
#define HMAX  256      // max hidden dim

// E-parallel scatter: agg[dst] += x[src], fire-and-forget f32 atomics at L2.
__global__ __launch_bounds__(256) void e_scatter(const int* __restrict__ ei,
                                                 const float* __restrict__ x,
                                                 float* __restrict__ agg, int E) {
  int Q = E >> 2;
  const int4* s4 = (const int4*)ei;
  const int4* d4 = (const int4*)(ei + E);
  int stride = gridDim.x * blockDim.x;
  for (int q = blockIdx.x * blockDim.x + threadIdx.x; q < Q; q += stride) {
    int4 s = s4[q];
    int4 d = d4[q];
    float vx = x[s.x], vy = x[s.y], vz = x[s.z], vw = x[s.w];
    atomicAdd(&agg[d.x], vx);
    atomicAdd(&agg[d.y], vy);
    atomicAdd(&agg[d.z], vz);
    atomicAdd(&agg[d.w], vw);
  }
  if (blockIdx.x == 0) {   // tail edges (E % 4)
    for (int e = (Q << 2) + threadIdx.x; e < E; e += 256)
      atomicAdd(&agg[ei[E + e]], x[ei[e]]);
  }
}

// Node MLP + per-graph pooling + final epilogue (device-scope ticket).
__global__ __launch_bounds__(256) void n_node(
    const float* __restrict__ agg, const int* __restrict__ batch,
    const float* __restrict__ Wl, const float* __restrict__ bl,
    const float* __restrict__ Wo, const float* __restrict__ b_out,
    float* __restrict__ gsum, float* __restrict__ gcnt,
    unsigned* __restrict__ done, float* __restrict__ out,
    int N, int H, int G) {
  __shared__ float sWl[HMAX], sbl[HMAX], sWo[HMAX];
  __shared__ float ls[GMAX], lc[GMAX];
  __shared__ unsigned ticket;
  int tid = threadIdx.x;
  if (tid < H) { sWl[tid] = Wl[tid]; sbl[tid] = bl[tid]; sWo[tid] = Wo[tid]; }
  if (tid < GMAX) { ls[tid] = 0.f; lc[tid] = 0.f; }
  __syncthreads();

  int i = blockIdx.x * blockDim.x + tid;
  if (i < N) {
    float a = agg[i], f = 0.f;
#pragma unroll 8
    for (int k = 0; k < H; ++k) {
      float hh = fmaf(a, sWl[k], sbl[k]);
      f = fmaf(fmaxf(hh, 0.f), sWo[k], f);
    }
    int g = batch[i];
    atomicAdd(&ls[g], f);
    atomicAdd(&lc[g], 1.f);
  }
  __syncthreads();
  if (tid < GMAX && lc[tid] != 0.f) {
    atomicAdd(&gsum[tid], ls[tid]);   // device-scope, memory-side
    atomicAdd(&gcnt[tid], lc[tid]);
  }
  __syncthreads();
  if (tid == 0)
    ticket = __hip_atomic_fetch_add(done, 1u, __ATOMIC_ACQ_REL,
                                    __HIP_MEMORY_SCOPE_AGENT);
  __syncthreads();
  if (ticket == gridDim.x - 1 && tid < G) {
    float s = __hip_atomic_load(&gsum[tid], __ATOMIC_RELAXED, __HIP_MEMORY_SCOPE_AGENT);
    float c = __hip_atomic_load(&gcnt[tid], __ATOMIC_RELAXED, __HIP_MEMORY_SCOPE_AGENT);
    out[tid] = fmaxf(s / fmaxf(c, 1.f) + b_out[0], 0.f);
  }
}

// ---------------- launch ----------------

extern "C" void kernel_launch(void* const* d_in, const int* in_sizes, int n_in,
                              void* d_out, int out_size, void* d_ws, size_t ws_size,
                              hipStream_t stream) {
  const float* x     = (const float*)d_in[0];
  const int*   ei    = (const int*)d_in[1];
  const int*   batch = (const int*)d_in[2];
  const float* Wl    = (const float*)d_in[3];
  const float* bl    = (const float*)d_in[4];
  const float* Wo    = (const float*)d_in[5];
  const float* bo    = (const float*)d_in[6];
  float* out = (float*)d_out;

  int N = in_sizes[0];        // 100000
  int E = in_sizes[1] / 2;    // 3200000
  int H = in_sizes[3];        // 256
  int G = out_size;           // 128

  // ws word layout: agg[N] | gsum[GMAX] | gcnt[GMAX] | done[4]
  float*    agg  = (float*)d_ws;
  float*    gsum = agg + N;
  float*    gcnt = gsum + GMAX;
  unsigned* done = (unsigned*)(gcnt + GMAX);

  hipMemsetAsync(d_ws, 0, ((size_t)N + 2 * GMAX + 4) * 4u, stream);

  int Q = E >> 2;
  int sg = (Q + 255) / 256;
  if (sg > 2048) sg = 2048;   // grid-stride past this (G11)
  if (sg < 1) sg = 1;
  e_scatter<<<sg, 256, 0, stream>>>(ei, x, agg, E);

  int nb = (N + 255) / 256;
  n_node<<<nb, 256, 0, stream>>>(agg, batch, Wl, bl, Wo, bo,
                                 gsum, gcnt, done, out, N, H, G);
}

// Round 4
// 250.018 us; speedup vs baseline: 1.0363x; 1.0363x over previous
//
#include <hip/hip_runtime.h>

// N=100000, E=3200000, H=256, G=128.
// R10: XCD-privatized L2-local atomic scatter.
// R9 evidence: default (agent-scope) global_atomic_add_f32 executes at the
// memory-side coherence point: WRITE_SIZE 99.8MB for a 400KB dst (~31B/atomic
// write-through), 169us for 3.2M atomics (~19G/s). Per-XCD L2s are not
// cross-coherent, so sc1 atomics bypass L2 entirely.
// Fix: 8 private agg copies (one per XCD, 3.2MB total). Each block keys its
// copy by s_getreg(HW_REG_XCC_ID) and issues WORKGROUP-scope atomics -> no
// sc1 -> RMW executes in the local XCD L2 (atomic across all workgroups of
// that XCD, which are the only writers of that copy). Dispatch-boundary L2
// writeback publishes the dirty lines; n_node sums the 8 copies per node
// (+3.2MB coalesced reads), then collapsed MLP
// f(a)=sum_k relu(a*Wl[k]+bl[k])*Wo[k], per-graph LDS pooling, ticket epilogue.

#define GMAX  128      // max graphs
#define HMAX  256      // max hidden dim
#define NXCD  8        // XCDs on MI355X (m09)

__device__ __forceinline__ int xcc_id() {
  int x;
  asm volatile("s_getreg_b32 %0, hwreg(HW_REG_XCC_ID)" : "=s"(x));
  return x & (NXCD - 1);
}

// E-parallel scatter: aggp[xcd][dst] += x[src], L2-local (workgroup-scope,
// fire-and-forget) f32 atomics.
__global__ __launch_bounds__(256) void e_scatter(const int* __restrict__ ei,
                                                 const float* __restrict__ x,
                                                 float* __restrict__ aggp,
                                                 int E, int N) {
  float* agg = aggp + (size_t)xcc_id() * (size_t)N;
  int Q = E >> 2;
  const int4* s4 = (const int4*)ei;
  const int4* d4 = (const int4*)(ei + E);
  int stride = gridDim.x * blockDim.x;
  for (int q = blockIdx.x * blockDim.x + threadIdx.x; q < Q; q += stride) {
    int4 s = s4[q];
    int4 d = d4[q];
    float vx = x[s.x], vy = x[s.y], vz = x[s.z], vw = x[s.w];
    (void)__hip_atomic_fetch_add(&agg[d.x], vx, __ATOMIC_RELAXED,
                                 __HIP_MEMORY_SCOPE_WORKGROUP);
    (void)__hip_atomic_fetch_add(&agg[d.y], vy, __ATOMIC_RELAXED,
                                 __HIP_MEMORY_SCOPE_WORKGROUP);
    (void)__hip_atomic_fetch_add(&agg[d.z], vz, __ATOMIC_RELAXED,
                                 __HIP_MEMORY_SCOPE_WORKGROUP);
    (void)__hip_atomic_fetch_add(&agg[d.w], vw, __ATOMIC_RELAXED,
                                 __HIP_MEMORY_SCOPE_WORKGROUP);
  }
  if (blockIdx.x == 0) {   // tail edges (E % 4)
    for (int e = (Q << 2) + threadIdx.x; e < E; e += 256)
      (void)__hip_atomic_fetch_add(&agg[ei[E + e]], x[ei[e]], __ATOMIC_RELAXED,
                                   __HIP_MEMORY_SCOPE_WORKGROUP);
  }
}

// Node MLP + per-graph pooling + final epilogue (device-scope ticket).
// Sums the NXCD private agg copies per node first.
__global__ __launch_bounds__(256) void n_node(
    const float* __restrict__ aggp, const int* __restrict__ batch,
    const float* __restrict__ Wl, const float* __restrict__ bl,
    const float* __restrict__ Wo, const float* __restrict__ b_out,
    float* __restrict__ gsum, float* __restrict__ gcnt,
    unsigned* __restrict__ done, float* __restrict__ out,
    int N, int H, int G) {
  __shared__ float sWl[HMAX], sbl[HMAX], sWo[HMAX];
  __shared__ float ls[GMAX], lc[GMAX];
  __shared__ unsigned ticket;
  int tid = threadIdx.x;
  if (tid < H) { sWl[tid] = Wl[tid]; sbl[tid] = bl[tid]; sWo[tid] = Wo[tid]; }
  if (tid < GMAX) { ls[tid] = 0.f; lc[tid] = 0.f; }
  __syncthreads();

  int i = blockIdx.x * blockDim.x + tid;
  if (i < N) {
    float a = 0.f;
#pragma unroll
    for (int c = 0; c < NXCD; ++c) a += aggp[(size_t)c * (size_t)N + i];
    float f = 0.f;
#pragma unroll 8
    for (int k = 0; k < H; ++k) {
      float hh = fmaf(a, sWl[k], sbl[k]);
      f = fmaf(fmaxf(hh, 0.f), sWo[k], f);
    }
    int g = batch[i];
    atomicAdd(&ls[g], f);
    atomicAdd(&lc[g], 1.f);
  }
  __syncthreads();
  if (tid < GMAX && lc[tid] != 0.f) {
    atomicAdd(&gsum[tid], ls[tid]);   // device-scope, memory-side
    atomicAdd(&gcnt[tid], lc[tid]);
  }
  __syncthreads();
  if (tid == 0)
    ticket = __hip_atomic_fetch_add(done, 1u, __ATOMIC_ACQ_REL,
                                    __HIP_MEMORY_SCOPE_AGENT);
  __syncthreads();
  if (ticket == gridDim.x - 1 && tid < G) {
    float s = __hip_atomic_load(&gsum[tid], __ATOMIC_RELAXED, __HIP_MEMORY_SCOPE_AGENT);
    float c = __hip_atomic_load(&gcnt[tid], __ATOMIC_RELAXED, __HIP_MEMORY_SCOPE_AGENT);
    out[tid] = fmaxf(s / fmaxf(c, 1.f) + b_out[0], 0.f);
  }
}

// ---------------- fallback path (ws too small) ----------------

__global__ __launch_bounds__(256) void fb_scatter(const int* __restrict__ ei,
                                                  const float* __restrict__ x,
                                                  float* __restrict__ agg, int E) {
  int t = blockIdx.x * blockDim.x + threadIdx.x;
  if (t < E) atomicAdd(&agg[ei[E + t]], x[ei[t]]);
}

__global__ __launch_bounds__(256) void fb_node(const float* __restrict__ agg,
                                               const int* __restrict__ batch,
                                               const float* __restrict__ Wl,
                                               const float* __restrict__ bl,
                                               const float* __restrict__ Wo,
                                               float* __restrict__ gsum,
                                               float* __restrict__ gcnt, int N, int H) {
  __shared__ float sWl[HMAX], sbl[HMAX], sWo[HMAX];
  __shared__ float ls[GMAX], lc[GMAX];
  int tid = threadIdx.x;
  if (tid < H) { sWl[tid] = Wl[tid]; sbl[tid] = bl[tid]; sWo[tid] = Wo[tid]; }
  if (tid < GMAX) { ls[tid] = 0.f; lc[tid] = 0.f; }
  __syncthreads();
  int i = blockIdx.x * blockDim.x + tid;
  if (i < N) {
    float a = agg[i], f = 0.f;
    for (int k = 0; k < H; ++k) {
      float hh = fmaf(a, sWl[k], sbl[k]);
      f = fmaf(fmaxf(hh, 0.f), sWo[k], f);
    }
    int g = batch[i];
    atomicAdd(&ls[g], f);
    atomicAdd(&lc[g], 1.f);
  }
  __syncthreads();
  if (tid < GMAX && lc[tid] != 0.f) {
    atomicAdd(&gsum[tid], ls[tid]);
    atomicAdd(&gcnt[tid], lc[tid]);
  }
}

__global__ void fb_final(const float* __restrict__ gsum,
                         const float* __restrict__ gcnt,
                         const float* __restrict__ b_out,
                         float* __restrict__ out, int G) {
  int g = blockIdx.x * blockDim.x + threadIdx.x;
  if (g < G) out[g] = fmaxf(gsum[g] / fmaxf(gcnt[g], 1.f) + b_out[0], 0.f);
}

// ---------------- launch ----------------

extern "C" void kernel_launch(void* const* d_in, const int* in_sizes, int n_in,
                              void* d_out, int out_size, void* d_ws, size_t ws_size,
                              hipStream_t stream) {
  const float* x     = (const float*)d_in[0];
  const int*   ei    = (const int*)d_in[1];
  const int*   batch = (const int*)d_in[2];
  const float* Wl    = (const float*)d_in[3];
  const float* bl    = (const float*)d_in[4];
  const float* Wo    = (const float*)d_in[5];
  const float* bo    = (const float*)d_in[6];
  float* out = (float*)d_out;

  int N = in_sizes[0];        // 100000
  int E = in_sizes[1] / 2;    // 3200000
  int H = in_sizes[3];        // 256
  int G = out_size;           // 128

  // ws word layout: aggp[NXCD*N] | gsum[GMAX] | gcnt[GMAX] | done[4]
  size_t aggw = (size_t)NXCD * (size_t)N;
  size_t need = (aggw + 2 * GMAX + 4) * 4u;

  if (ws_size >= need && H <= HMAX && G <= GMAX) {
    float*    aggp = (float*)d_ws;
    float*    gsum = aggp + aggw;
    float*    gcnt = gsum + GMAX;
    unsigned* done = (unsigned*)(gcnt + GMAX);

    hipMemsetAsync(d_ws, 0, need, stream);

    int Q = E >> 2;
    int sg = (Q + 255) / 256;
    if (sg > 2048) sg = 2048;   // grid-stride past this (G11)
    if (sg < 1) sg = 1;
    e_scatter<<<sg, 256, 0, stream>>>(ei, x, aggp, E, N);

    int nb = (N + 255) / 256;
    n_node<<<nb, 256, 0, stream>>>(aggp, batch, Wl, bl, Wo, bo,
                                   gsum, gcnt, done, out, N, H, G);
  } else {
    float* agg  = (float*)d_ws;
    float* gsum = agg + N;
    float* gcnt = gsum + GMAX;
    hipMemsetAsync(d_ws, 0, ((size_t)N + 2 * GMAX) * 4u, stream);
    fb_scatter<<<(E + 255) / 256, 256, 0, stream>>>(ei, x, agg, E);
    fb_node<<<(N + 255) / 256, 256, 0, stream>>>(agg, batch, Wl, bl, Wo,
                                                 gsum, gcnt, N, H);
    fb_final<<<1, 256, 0, stream>>>(gsum, gcnt, bo, out, G);
  }
}